// Round 17
// baseline (7922.824 us; speedup 1.0000x reference)
//
#include <hip/hip_runtime.h>
#include <math.h>

#define B_   32
#define L_   197
#define E_   384
#define DI_  768
#define DS_  16
#define DR_  24
#define NP_  196
#define ROWS (B_ * L_)         // 6304
#define OUT0 (ROWS * E_)       // 2420736
#define FEAT (B_ * E_ * NP_)   // 2408448
#define LOG2E 1.4426950408889634f

typedef __attribute__((ext_vector_type(8))) short bf16x8;
typedef __attribute__((ext_vector_type(4))) float f32x4;
typedef __attribute__((ext_vector_type(2))) __fp16 half2v;

#if __has_builtin(__builtin_amdgcn_exp2f)
#define EXP2(x) __builtin_amdgcn_exp2f(x)
#else
#define EXP2(x) __expf((x) * 0.6931471805599453f)
#endif

// async global->LDS, 16B per lane
__device__ __forceinline__ void gll16(const void* g, void* l) {
    __builtin_amdgcn_global_load_lds((const __attribute__((address_space(1))) void*)g,
                                     (__attribute__((address_space(3))) void*)l, 16, 0, 0);
}

__device__ __forceinline__ float silu_f(float x) { return x / (1.f + __expf(-x)); }

__device__ __forceinline__ unsigned short f2bf(float x) {
    unsigned int u = __float_as_uint(x);
    u += 0x7fffu + ((u >> 16) & 1u);
    return (unsigned short)(u >> 16);
}
__device__ __forceinline__ float bf2f(unsigned short u) {
    return __uint_as_float((unsigned int)u << 16);
}
__device__ __forceinline__ float bflo(unsigned int u) { return __uint_as_float(u << 16); }
__device__ __forceinline__ float bfhi(unsigned int u) {
    return __uint_as_float(u & 0xffff0000u);
}

// ---------------- fp32 -> bf16 bulk convert (weights; n % 4 == 0) ----------------
__global__ __launch_bounds__(256) void cvt_bf16_kernel(const float* __restrict__ in,
                                                       unsigned short* __restrict__ out,
                                                       int n4) {
    int idx = blockIdx.x * 256 + threadIdx.x;
    if (idx >= n4) return;
    float4 v = *(const float4*)&in[idx * 4];
    ushort4 o = {f2bf(v.x), f2bf(v.y), f2bf(v.z), f2bf(v.w)};
    *(ushort4*)&out[idx * 4] = o;
}

// ---------------- im2col for patch embedding ----------------
__global__ __launch_bounds__(256) void im2col_kernel(const float* __restrict__ x,
                                                     float* __restrict__ xcol) {
    int idx = blockIdx.x * 256 + threadIdx.x;
    if (idx >= B_ * NP_ * 768) return;
    int k = idx % 768;
    int bp = idx / 768;
    int pi = bp % NP_, b = bp / NP_;
    int gi = pi / 14, gj = pi % 14;
    int c = k >> 8, r = k & 255, p = r >> 4, q = r & 15;
    xcol[idx] = x[((size_t)(b * 3 + c) * 224 + gi * 16 + p) * 224 + gj * 16 + q];
}

// ---------------- assemble hidden: patches + cls + pos ----------------
__global__ __launch_bounds__(256) void assemble_kernel(const float* __restrict__ patchbuf,
                                                       const float* __restrict__ cls,
                                                       const float* __restrict__ pos,
                                                       float* __restrict__ hidden) {
    int idx = blockIdx.x * 256 + threadIdx.x;
    if (idx >= ROWS * E_) return;
    int e = idx % E_;
    int bt = idx / E_;
    int tok = bt % L_, b = bt / L_;
    float v;
    if (tok == 98) v = cls[e];
    else {
        int pi = tok < 98 ? tok : tok - 1;
        v = patchbuf[(size_t)(b * NP_ + pi) * E_ + e];
    }
    hidden[idx] = v + pos[tok * E_ + e];
}

// ---------------- 128x128 bf16 MFMA GEMM, global_load_lds staging ----------------
__global__ __launch_bounds__(256) void gemm128_kernel(
    const void* Av, int lda, const unsigned short* __restrict__ W,
    const float* __restrict__ bias, void* C, unsigned short* __restrict__ aux,
    int ldc, int M, int N, int K, int amode, int cmode) {
    __shared__ unsigned short As[128][32];
    __shared__ unsigned short Ws[128][32];
    const int tid = threadIdx.x;
    const int wave = tid >> 6, lane = tid & 63;
    const int wr = wave >> 1, wc = wave & 1;
    const int bm = blockIdx.y * 128, bn = blockIdx.x * 128;
    const int fr = lane & 15, fq = lane >> 4;
    f32x4 acc[4][4] = {};

    for (int k0 = 0; k0 < K; k0 += 32) {
        __syncthreads();
        if (amode == 4) {
            const unsigned short* A = (const unsigned short*)Av;
#pragma unroll
            for (int it = 0; it < 2; ++it) {
                int c = it * 256 + tid;
                int row = c >> 2, kq = c & 3;
                gll16(&A[(size_t)(bm + row) * lda + k0 + kq * 8], &As[row][kq * 8]);
            }
        } else {
            const float* A = (const float*)Av;
            const int r = tid >> 3, c4 = tid & 7;
            const int kbase = k0 + c4 * 4;
#pragma unroll
            for (int it = 0; it < 4; ++it) {
                int row = it * 32 + r;
                int gm = bm + row;
                ushort4 ua = {0, 0, 0, 0};
                if (gm < M) {
                    float4 va = *(const float4*)&A[(size_t)gm * lda + kbase];
                    ua.x = f2bf(va.x); ua.y = f2bf(va.y);
                    ua.z = f2bf(va.z); ua.w = f2bf(va.w);
                }
                *(ushort4*)&As[row][c4 * 4] = ua;
            }
        }
#pragma unroll
        for (int it = 0; it < 2; ++it) {
            int c = it * 256 + tid;
            int row = c >> 2, kq = c & 3;
            gll16(&W[(size_t)(bn + row) * K + k0 + kq * 8], &Ws[row][kq * 8]);
        }
        __syncthreads();
        bf16x8 af[4], bfr[4];
#pragma unroll
        for (int i = 0; i < 4; ++i) {
            af[i]  = *(const bf16x8*)&As[wr * 64 + i * 16 + fr][fq * 8];
            bfr[i] = *(const bf16x8*)&Ws[wc * 64 + i * 16 + fr][fq * 8];
        }
#pragma unroll
        for (int i = 0; i < 4; ++i)
#pragma unroll
            for (int j = 0; j < 4; ++j)
                acc[i][j] =
                    __builtin_amdgcn_mfma_f32_16x16x32_bf16(af[i], bfr[j], acc[i][j], 0, 0, 0);
    }

#pragma unroll
    for (int j = 0; j < 4; ++j) {
        int n = bn + wc * 64 + j * 16 + fr;
        if (n >= N) continue;
        float bv = bias ? bias[n] : 0.f;
#pragma unroll
        for (int i = 0; i < 4; ++i) {
#pragma unroll
            for (int rr = 0; rr < 4; ++rr) {
                int m = bm + wr * 64 + i * 16 + fq * 4 + rr;
                if (m < M) {
                    float v = acc[i][j][rr] + bv;
                    if (cmode == 0) ((float*)C)[(size_t)m * ldc + n] = v;
                    else {
                        ((unsigned short*)C)[(size_t)m * ldc + n] = f2bf(v);
                        if (cmode == 2 && n >= 768)
                            aux[(size_t)m * 768 + (n - 768)] = f2bf(silu_f(v));
                    }
                }
            }
        }
    }
}

// ---------------- 64x64 bf16 MFMA GEMM (skinny shapes), gll staging ----------------
__global__ __launch_bounds__(256) void gemm64_kernel(
    const void* A0v, const void* A1v, int lda,
    const unsigned short* __restrict__ W0, const unsigned short* __restrict__ W1,
    void* C0, void* C1, int ldc, int M, int N, int K, int amode, int cmode) {
    __shared__ unsigned short As[64][32];
    __shared__ unsigned short Ws[64][32];
    const int tid = threadIdx.x;
    const int wave = tid >> 6, lane = tid & 63;
    const int wr = wave >> 1, wc = wave & 1;
    const int bm = blockIdx.y * 64, bn = blockIdx.x * 64;
    const int fr = lane & 15, fq = lane >> 4;
    const int row = tid >> 2, kq = tid & 3;
    const unsigned short* W = blockIdx.z ? W1 : W0;
    void* C = blockIdx.z ? C1 : C0;
    const void* Av = blockIdx.z ? A1v : A0v;
    f32x4 acc[2][2] = {};

    for (int k0 = 0; k0 < K; k0 += 32) {
        __syncthreads();
        if (amode == 4) {
            const unsigned short* A = (const unsigned short*)Av;
            gll16(&A[(size_t)(bm + row) * lda + k0 + kq * 8], &As[row][kq * 8]);
        } else {
            const unsigned short* Af = (const unsigned short*)A0v;
            const unsigned short* Ab = (const unsigned short*)A1v;
            int gm = bm + row;
            ushort4 a0 = {0, 0, 0, 0}, a1 = {0, 0, 0, 0};
            if (gm < M) {
                size_t off = (size_t)gm * lda + k0 + kq * 8;
                ushort4 f0 = *(const ushort4*)&Af[off];
                ushort4 b0 = *(const ushort4*)&Ab[off];
                ushort4 f1 = *(const ushort4*)&Af[off + 4];
                ushort4 b1 = *(const ushort4*)&Ab[off + 4];
                a0.x = f2bf((bf2f(f0.x) + bf2f(b0.x)) * 0.5f);
                a0.y = f2bf((bf2f(f0.y) + bf2f(b0.y)) * 0.5f);
                a0.z = f2bf((bf2f(f0.z) + bf2f(b0.z)) * 0.5f);
                a0.w = f2bf((bf2f(f0.w) + bf2f(b0.w)) * 0.5f);
                a1.x = f2bf((bf2f(f1.x) + bf2f(b1.x)) * 0.5f);
                a1.y = f2bf((bf2f(f1.y) + bf2f(b1.y)) * 0.5f);
                a1.z = f2bf((bf2f(f1.z) + bf2f(b1.z)) * 0.5f);
                a1.w = f2bf((bf2f(f1.w) + bf2f(b1.w)) * 0.5f);
            }
            *(ushort4*)&As[row][kq * 8] = a0;
            *(ushort4*)&As[row][kq * 8 + 4] = a1;
        }
        gll16(&W[(size_t)(bn + row) * K + k0 + kq * 8], &Ws[row][kq * 8]);
        __syncthreads();
        bf16x8 af[2], bfr[2];
#pragma unroll
        for (int i = 0; i < 2; ++i) {
            af[i]  = *(const bf16x8*)&As[wr * 32 + i * 16 + fr][fq * 8];
            bfr[i] = *(const bf16x8*)&Ws[wc * 32 + i * 16 + fr][fq * 8];
        }
#pragma unroll
        for (int i = 0; i < 2; ++i)
#pragma unroll
            for (int j = 0; j < 2; ++j)
                acc[i][j] =
                    __builtin_amdgcn_mfma_f32_16x16x32_bf16(af[i], bfr[j], acc[i][j], 0, 0, 0);
    }

#pragma unroll
    for (int j = 0; j < 2; ++j) {
        int n = bn + wc * 32 + j * 16 + fr;
        if (n >= N) continue;
#pragma unroll
        for (int i = 0; i < 2; ++i) {
#pragma unroll
            for (int rr = 0; rr < 4; ++rr) {
                int m = bm + wr * 32 + i * 16 + fq * 4 + rr;
                if (m < M) {
                    float v = acc[i][j][rr];
                    if (cmode == 0) ((float*)C)[(size_t)m * ldc + n] = v;
                    else ((unsigned short*)C)[(size_t)m * ldc + n] = f2bf(v);
                }
            }
        }
    }
}

// ------- fused residual += hidden ; hn(bf16) = LayerNorm(residual) -------------------
__global__ __launch_bounds__(256) void resid_ln_kernel(float* __restrict__ residual,
                                                       const float* __restrict__ hidden,
                                                       const float* __restrict__ w,
                                                       const float* __restrict__ b,
                                                       unsigned short* __restrict__ outb,
                                                       float* __restrict__ outf,
                                                       int nrows) {
    int row = blockIdx.x * 4 + (threadIdx.x >> 6);
    int lane = threadIdx.x & 63;
    if (row >= nrows) return;
    const float* rp = residual + (size_t)row * E_;
    const float* hp = hidden + (size_t)row * E_;
    float v[6];
    float sum = 0.f;
#pragma unroll
    for (int i = 0; i < 6; ++i) {
        int c = lane + i * 64;
        float x = rp[c] + hp[c];
        v[i] = x;
        sum += x;
    }
#pragma unroll
    for (int o = 32; o; o >>= 1) sum += __shfl_xor(sum, o);
    float mean = sum * (1.f / E_);
    float vs = 0.f;
#pragma unroll
    for (int i = 0; i < 6; ++i) {
        float d = v[i] - mean;
        vs += d * d;
    }
#pragma unroll
    for (int o = 32; o; o >>= 1) vs += __shfl_xor(vs, o);
    float rstd = rsqrtf(vs * (1.f / E_) + 1e-5f);
#pragma unroll
    for (int i = 0; i < 6; ++i) {
        int c = lane + i * 64;
        residual[(size_t)row * E_ + c] = v[i];
        float o = (v[i] - mean) * rstd * w[c] + b[c];
        if (outb) outb[(size_t)row * E_ + c] = f2bf(o);
        else outf[(size_t)row * E_ + c] = o;
    }
}

// ------- causal conv1d + SiLU -> bf16, 4 d's/thread (z handled by in_proj epilogue) ---
__global__ __launch_bounds__(256) void conv_silu4_kernel(const unsigned short* __restrict__ xz,
                                                         const float* __restrict__ cw_f,
                                                         const float* __restrict__ cb_f,
                                                         const float* __restrict__ cw_b,
                                                         const float* __restrict__ cb_b,
                                                         unsigned short* __restrict__ xc_f,
                                                         unsigned short* __restrict__ xc_b) {
    int rev = blockIdx.y;
    const float* cw = rev ? cw_b : cw_f;
    const float* cb = rev ? cb_b : cb_f;
    unsigned short* xc = rev ? xc_b : xc_f;
    int idx = blockIdx.x * 256 + threadIdx.x;      // over B_*L_*DI_/4
    if (idx >= B_ * L_ * DI_ / 4) return;
    int d4 = idx % (DI_ / 4);
    int bt = idx / (DI_ / 4);
    int t = bt % L_, b = bt / L_;
    int d = d4 * 4;
    float4 w0 = *(const float4*)&cw[(d + 0) * 4];
    float4 w1 = *(const float4*)&cw[(d + 1) * 4];
    float4 w2 = *(const float4*)&cw[(d + 2) * 4];
    float4 w3 = *(const float4*)&cw[(d + 3) * 4];
    float4 cbv = *(const float4*)&cb[d];
    float acc0 = cbv.x, acc1 = cbv.y, acc2 = cbv.z, acc3 = cbv.w;
#pragma unroll
    for (int k = 0; k < 4; ++k) {
        int tt = t - 3 + k;
        if (tt >= 0) {
            int pos = rev ? (L_ - 1 - tt) : tt;
            ushort4 xv = *(const ushort4*)&xz[(size_t)(b * L_ + pos) * 1536 + d];
            float wk0 = (&w0.x)[k], wk1 = (&w1.x)[k], wk2 = (&w2.x)[k], wk3 = (&w3.x)[k];
            acc0 += wk0 * bf2f(xv.x);
            acc1 += wk1 * bf2f(xv.y);
            acc2 += wk2 * bf2f(xv.z);
            acc3 += wk3 * bf2f(xv.w);
        }
    }
    ushort4 o = {f2bf(silu_f(acc0)), f2bf(silu_f(acc1)), f2bf(silu_f(acc2)),
                 f2bf(silu_f(acc3))};
    *(ushort4*)&xc[(size_t)bt * DI_ + d] = o;
}

// ---------------- chunk-parallel SSM scan, 8 d's/block, XCD-affinity swizzle ----------
// f16 a-cache (spill-free via launch_bounds(512,6)); BCs stride 426 -> odd dword stride,
// conflict-free b64 reads across 16 n-lanes.
__global__ __launch_bounds__(512, 6) void scan8_kernel(
    const unsigned short* __restrict__ xcl_f, const unsigned short* __restrict__ xcl_b,
    const unsigned short* __restrict__ xdbl_f, const unsigned short* __restrict__ xdbl_b,
    const unsigned short* __restrict__ zsilu,
    const float* __restrict__ dtw_f, const float* __restrict__ dtw_b,
    const float* __restrict__ dtb_f, const float* __restrict__ dtb_b,
    const float* __restrict__ Alog_f, const float* __restrict__ Alog_b,
    const float* __restrict__ Dv_f, const float* __restrict__ Dv_b,
    unsigned short* __restrict__ yout_f, unsigned short* __restrict__ yout_b) {
    int bid = blockIdx.x;
    int xcd = bid & 7;
    int rdec = bid >> 3;
    int dg = rdec % 96;
    int ph = rdec / 96;
    int p = ph * 8 + xcd;
    const int b = p >> 1, dir = p & 1;
    const int d0 = dg * 8;

    const unsigned short* xcl = dir ? xcl_b : xcl_f;
    const unsigned short* xdbl = dir ? xdbl_b : xdbl_f;
    const float* dtw  = dir ? dtw_b : dtw_f;
    const float* dtbp = dir ? dtb_b : dtb_f;
    const float* Alog = dir ? Alog_b : Alog_f;
    const float* Dv   = dir ? Dv_b : Dv_f;
    unsigned short* yout = dir ? yout_b : yout_f;
    const int tid = threadIdx.x;

    __shared__ float dt_s[8][200];
    __shared__ unsigned short g_s[8][200];
    __shared__ unsigned short u_s[8][200];
    __shared__ unsigned short z_s[8][200];
    __shared__ unsigned short y_s[8][200];
    // BCs[n]: records of {B[2q],B[2q+1],C[2q],C[2q+1]}; row = 426 shorts = 213 dwords (odd)
    __shared__ unsigned short BCs[16][426];
    __shared__ float Ps[8][4][16], Ss[8][4][16], hin[8][4][16];
    __shared__ float dtw_s[8][24];

    if (tid < 192) dtw_s[tid / 24][tid % 24] = dtw[(d0 + tid / 24) * 24 + tid % 24];
    __syncthreads();

    // stage B, C (pure bf16 copy into interleaved records)
    for (int e = tid; e < 3200; e += 512) {
        int t = e >> 4, nn = e & 15;
        unsigned short Bv = 0, Cv = 0;
        if (t < L_) {
            const unsigned short* xr = &xdbl[(size_t)(b * L_ + t) * 56];
            Bv = xr[24 + nn];
            Cv = xr[40 + nn];
        }
        int base = (t >> 1) * 4 + (t & 1);
        BCs[nn][base] = Bv;
        BCs[nn][base + 2] = Cv;
    }
    // stage dt (f32 from bf16 inputs), g=dt*u, u, z
    for (int e = tid; e < 800; e += 512) {
        int dd = e & 7, q = e >> 3;
        float dtv[2], uv[2], zv[2];
#pragma unroll
        for (int h = 0; h < 2; ++h) {
            int t = 2 * q + h;
            dtv[h] = 0.f; uv[h] = 0.f; zv[h] = 0.f;
            if (t < L_) {
                size_t row = (size_t)(b * L_ + t);
                int pos = dir ? (L_ - 1 - t) : t;
                uv[h] = bf2f(xcl[row * DI_ + d0 + dd]);
                zv[h] = bf2f(zsilu[(size_t)(b * L_ + pos) * DI_ + d0 + dd]);
                const unsigned short* xr = &xdbl[row * 56];
                float acc = dtbp[d0 + dd];
#pragma unroll
                for (int rr = 0; rr < 24; ++rr) acc += bf2f(xr[rr]) * dtw_s[dd][rr];
                dtv[h] = (acc > 20.f) ? acc : log1pf(__expf(acc));
            }
        }
        *(float2*)&dt_s[dd][2 * q] = make_float2(dtv[0], dtv[1]);
        ushort2 ug = {f2bf(dtv[0] * uv[0]), f2bf(dtv[1] * uv[1])};
        ushort2 uu = {f2bf(uv[0]), f2bf(uv[1])};
        ushort2 uz = {f2bf(zv[0]), f2bf(zv[1])};
        *(ushort2*)&g_s[dd][2 * q] = ug;
        *(ushort2*)&u_s[dd][2 * q] = uu;
        *(ushort2*)&z_s[dd][2 * q] = uz;
    }
    __syncthreads();

    const int dd = tid >> 6;
    const int tt = (tid >> 4) & 3;
    const int n = tid & 15;
    const float An = -__expf(Alog[(d0 + dd) * DS_ + n]) * LOG2E;
    const int t0 = tt * 50;            // even -> pair-aligned

    const float* dtp = &dt_s[dd][t0];
    const unsigned short* gp = &g_s[dd][t0];
    const unsigned short* BCp = &BCs[n][(t0 >> 1) * 4];

    // pass 1: chunk (P,S) in f32; cache a-pairs as f16 in VGPRs
    half2v acache[25];
    float P = 1.f, S = 0.f;
#pragma unroll
    for (int i = 0; i < 50; i += 2) {
        float2 dt2 = *(const float2*)&dtp[i];
        unsigned int g2 = *(const unsigned int*)&gp[i];
        unsigned int B2 = *(const unsigned int*)&BCp[(i >> 1) * 4];
        float a0 = EXP2(dt2.x * An);
        float a1 = EXP2(dt2.y * An);
        acache[i >> 1] = __builtin_amdgcn_cvt_pkrtz(a0, a1);
        S = S * a0 + bflo(g2) * bflo(B2);
        S = S * a1 + bfhi(g2) * bfhi(B2);
        P *= a0 * a1;
    }
    Ps[dd][tt][n] = P;
    Ss[dd][tt][n] = S;
    __syncthreads();
    if (tid < 128) {
        int cdd = tid >> 4, cn = tid & 15;
        float h = 0.f;
#pragma unroll
        for (int c = 0; c < 4; ++c) {
            hin[cdd][c][cn] = h;
            h = Ps[cdd][c][cn] * h + Ss[cdd][c][cn];
        }
    }
    __syncthreads();

    // pass 2: replay with cached f16 a; 3 groups of 16 t + 2-t tail
    float h = hin[dd][tt][n];
    const float Dval = Dv[d0 + dd];
    const bool up8 = (n & 8) != 0;
    const bool up4 = (n & 4) != 0;
    const bool up2 = (n & 2) != 0;
    const bool up1 = (n & 1) != 0;
#pragma unroll
    for (int grp = 0; grp < 3; ++grp) {
        const int base = grp * 16;
        float pv[16];
#pragma unroll
        for (int i = 0; i < 16; i += 2) {
            const int q = (base + i) >> 1;
            unsigned int g2 = *(const unsigned int*)&gp[base + i];
            uint2 bc = *(const uint2*)&BCp[q * 4];
            half2v ah = acache[q];
            h = (float)ah.x * h + bflo(g2) * bflo(bc.x);
            pv[i] = h * bflo(bc.y);
            h = (float)ah.y * h + bfhi(g2) * bfhi(bc.x);
            pv[i + 1] = h * bfhi(bc.y);
        }
#pragma unroll
        for (int j = 0; j < 8; ++j) {
            float send = up8 ? pv[j] : pv[j + 8];
            float recv = __shfl_xor(send, 8);
            pv[j] = (up8 ? pv[j + 8] : pv[j]) + recv;
        }
#pragma unroll
        for (int j = 0; j < 4; ++j) {
            float send = up4 ? pv[j] : pv[j + 4];
            float recv = __shfl_xor(send, 4);
            pv[j] = (up4 ? pv[j + 4] : pv[j]) + recv;
        }
#pragma unroll
        for (int j = 0; j < 2; ++j) {
            float send = up2 ? pv[j] : pv[j + 2];
            float recv = __shfl_xor(send, 2);
            pv[j] = (up2 ? pv[j + 2] : pv[j]) + recv;
        }
        {
            float send = up1 ? pv[0] : pv[1];
            float recv = __shfl_xor(send, 1);
            pv[0] = (up1 ? pv[1] : pv[0]) + recv;
        }
        int t = t0 + base + n;
        if (t < L_) {
            float yv = (pv[0] + bf2f(u_s[dd][t]) * Dval) * bf2f(z_s[dd][t]);
            y_s[dd][t] = f2bf(yv);
        }
    }
    // tail: t = t0+48, t0+49
    {
        unsigned int g2 = *(const unsigned int*)&gp[48];
        uint2 bc = *(const uint2*)&BCp[24 * 4];
        half2v ah = acache[24];
#pragma unroll
        for (int half = 0; half < 2; ++half) {
            float av = half ? (float)ah.y : (float)ah.x;
            float gv = half ? bfhi(g2) : bflo(g2);
            float Bv = half ? bfhi(bc.x) : bflo(bc.x);
            float Cv = half ? bfhi(bc.y) : bflo(bc.y);
            h = av * h + gv * Bv;
            float y = h * Cv;
            y += __shfl_xor(y, 1);
            y += __shfl_xor(y, 2);
            y += __shfl_xor(y, 4);
            y += __shfl_xor(y, 8);
            int t = t0 + 48 + half;
            if (n == 0 && t < L_)
                y_s[dd][t] = f2bf((y + bf2f(u_s[dd][t]) * Dval) * bf2f(z_s[dd][t]));
        }
    }
    __syncthreads();
    for (int e = tid; e < 1600; e += 512) {
        int dd2 = e & 7, t = e >> 3;
        if (t < L_) {
            int pos = dir ? (L_ - 1 - t) : t;
            yout[(size_t)(b * L_ + pos) * DI_ + d0 + dd2] = y_s[dd2][t];
        }
    }
}

// ---------------- feature extraction ----------------
__global__ __launch_bounds__(256) void feat_kernel(const float* __restrict__ hidden,
                                                   float* __restrict__ out) {
    int idx = blockIdx.x * 256 + threadIdx.x;
    if (idx >= FEAT) return;
    int p = idx % NP_;
    int be = idx / NP_;
    int e = be % E_, b = be / E_;
    int tok = p < 98 ? p : p + 1;
    out[idx] = hidden[(size_t)(b * L_ + tok) * E_ + e];
}

extern "C" void kernel_launch(void* const* d_in, const int* in_sizes, int n_in, void* d_out,
                              int out_size, void* d_ws, size_t ws_size, hipStream_t stream) {
    const float* x        = (const float*)d_in[0];
    const float* patch_w  = (const float*)d_in[1];
    const float* patch_b  = (const float*)d_in[2];
    const float* cls_tok  = (const float*)d_in[3];
    const float* pos_emb  = (const float*)d_in[4];
    const float* norm_w   = (const float*)d_in[5];
    const float* norm_b   = (const float*)d_in[6];
    const float* in_proj  = (const float*)d_in[7];
    const float* conv_w   = (const float*)d_in[8];
    const float* conv_b   = (const float*)d_in[9];
    const float* xproj_w  = (const float*)d_in[10];
    const float* dtproj_w = (const float*)d_in[11];
    const float* dtproj_b = (const float*)d_in[12];
    const float* A_log    = (const float*)d_in[13];
    const float* D_param  = (const float*)d_in[14];
    const float* conv_wb  = (const float*)d_in[15];
    const float* conv_bb  = (const float*)d_in[16];
    const float* xproj_wb = (const float*)d_in[17];
    const float* dtproj_wb= (const float*)d_in[18];
    const float* dtproj_bb= (const float*)d_in[19];
    const float* A_logb   = (const float*)d_in[20];
    const float* D_paramb = (const float*)d_in[21];
    const float* out_proj = (const float*)d_in[22];
    const float* normf_w  = (const float*)d_in[23];
    const float* normf_b  = (const float*)d_in[24];
    float* out = (float*)d_out;

    float* ws       = (float*)d_ws;
    float* residual = ws;                                    // 9.68 MB
    float* hidden   = residual + OUT0;                       // 9.68 MB
    unsigned short* xz = (unsigned short*)(hidden + OUT0);   // 19.36 MB
    unsigned short* xcl_f = xz + (size_t)ROWS * 1536;        // 9.68 MB
    unsigned short* xcl_b = xcl_f + (size_t)ROWS * DI_;      // 9.68 MB
    unsigned short* zsilu = xcl_b + (size_t)ROWS * DI_;      // 9.68 MB
    unsigned short* xdbl_f = zsilu + (size_t)ROWS * DI_;     // 0.71 MB (bf16)
    unsigned short* xdbl_b = xdbl_f + (size_t)ROWS * 56;     // 0.71 MB
    unsigned short* yout_f = xdbl_b + (size_t)ROWS * 56;     // 9.68 MB
    unsigned short* yout_b = yout_f + (size_t)ROWS * DI_;    // 9.68 MB
    // pre-converted bf16 weights (~47.2 MB)
    unsigned short* wb_inproj  = yout_b + (size_t)ROWS * DI_;
    unsigned short* wb_outproj = wb_inproj + (size_t)24 * 1536 * E_;
    unsigned short* wb_xproj_f = wb_outproj + (size_t)24 * E_ * DI_;
    unsigned short* wb_xproj_b = wb_xproj_f + (size_t)24 * 56 * DI_;
    unsigned short* wb_patch   = wb_xproj_b + (size_t)24 * 56 * DI_;
    // overlays (timeline-disjoint)
    unsigned short* hn = yout_f;       // bf16; alive LN -> in_proj
    float* xcol     = (float*)xz;      // pre-layer only
    float* patchbuf = (float*)yout_f;  // pre-layer only

    hipMemsetAsync(residual, 0, (size_t)OUT0 * sizeof(float), stream);

    // weight conversion (once per launch)
    {
        int n;
        n = 24 * 1536 * E_ / 4;
        hipLaunchKernelGGL(cvt_bf16_kernel, dim3((n + 255) / 256), dim3(256), 0, stream,
                           in_proj, wb_inproj, n);
        n = 24 * E_ * DI_ / 4;
        hipLaunchKernelGGL(cvt_bf16_kernel, dim3((n + 255) / 256), dim3(256), 0, stream,
                           out_proj, wb_outproj, n);
        n = 24 * 56 * DI_ / 4;
        hipLaunchKernelGGL(cvt_bf16_kernel, dim3((n + 255) / 256), dim3(256), 0, stream,
                           xproj_w, wb_xproj_f, n);
        hipLaunchKernelGGL(cvt_bf16_kernel, dim3((n + 255) / 256), dim3(256), 0, stream,
                           xproj_wb, wb_xproj_b, n);
        n = E_ * 768 / 4;
        hipLaunchKernelGGL(cvt_bf16_kernel, dim3((n + 255) / 256), dim3(256), 0, stream,
                           patch_w, wb_patch, n);
    }

    // patch embedding
    hipLaunchKernelGGL(im2col_kernel, dim3((B_ * NP_ * 768 + 255) / 256), dim3(256), 0, stream,
                       x, xcol);
    {
        dim3 grid((E_ + 127) / 128, (B_ * NP_ + 127) / 128, 1);
        hipLaunchKernelGGL(gemm128_kernel, grid, dim3(256), 0, stream, (const void*)xcol, 768,
                           wb_patch, patch_b, (void*)patchbuf, (unsigned short*)nullptr, E_,
                           B_ * NP_, E_, 768, 0, 0);
    }
    hipLaunchKernelGGL(assemble_kernel, dim3((ROWS * E_ + 255) / 256), dim3(256), 0, stream,
                       patchbuf, cls_tok, pos_emb, hidden);

    int fidx = 0;
    for (int i = 0; i < 24; ++i) {
        hipLaunchKernelGGL(resid_ln_kernel, dim3(ROWS / 4), dim3(256), 0, stream, residual,
                           hidden, norm_w + i * E_, norm_b + i * E_, hn, (float*)nullptr,
                           ROWS);
        // in_proj: A = hn (bf16, gll), C = xz (bf16) + zsilu epilogue
        {
            dim3 grid((1536 + 127) / 128, (ROWS + 127) / 128, 1);
            hipLaunchKernelGGL(gemm128_kernel, grid, dim3(256), 0, stream, (const void*)hn, E_,
                               wb_inproj + (size_t)i * 1536 * E_, nullptr, (void*)xz, zsilu,
                               1536, ROWS, 1536, E_, 4, 2);
        }
        hipLaunchKernelGGL(conv_silu4_kernel, dim3(B_ * L_ * DI_ / 4 / 256, 2), dim3(256), 0,
                           stream, xz, conv_w + (size_t)i * DI_ * 4, conv_b + (size_t)i * DI_,
                           conv_wb + (size_t)i * DI_ * 4, conv_bb + (size_t)i * DI_, xcl_f,
                           xcl_b);
        // x_proj both dirs, 64x64 tiles (bf16 A gll, bf16 C)
        {
            dim3 grid(1, (ROWS + 63) / 64, 2);
            hipLaunchKernelGGL(gemm64_kernel, grid, dim3(256), 0, stream, (const void*)xcl_f,
                               (const void*)xcl_b, DI_, wb_xproj_f + (size_t)i * 56 * DI_,
                               wb_xproj_b + (size_t)i * 56 * DI_, (void*)xdbl_f,
                               (void*)xdbl_b, 56, ROWS, 56, DI_, 4, 1);
        }
        hipLaunchKernelGGL(scan8_kernel, dim3(6144), dim3(512), 0, stream, xcl_f, xcl_b,
                           xdbl_f, xdbl_b, zsilu, dtproj_w + (size_t)i * DI_ * DR_,
                           dtproj_wb + (size_t)i * DI_ * DR_, dtproj_b + (size_t)i * DI_,
                           dtproj_bb + (size_t)i * DI_, A_log + (size_t)i * DI_ * DS_,
                           A_logb + (size_t)i * DI_ * DS_, D_param + (size_t)i * DI_,
                           D_paramb + (size_t)i * DI_, yout_f, yout_b);
        // out_proj: A = 0.5*(yout_f + yout_b) (bf16), 64x64 tiles, C = hidden (f32)
        {
            dim3 grid((E_ + 63) / 64, (ROWS + 63) / 64, 1);
            hipLaunchKernelGGL(gemm64_kernel, grid, dim3(256), 0, stream, (const void*)yout_f,
                               (const void*)yout_b, DI_, wb_outproj + (size_t)i * E_ * DI_,
                               nullptr, (void*)hidden, nullptr, E_, ROWS, E_, DI_, 1, 0);
        }
        if (i == 5 || i == 11 || i == 17 || i == 23) {
            hipLaunchKernelGGL(feat_kernel, dim3(FEAT / 256), dim3(256), 0, stream, hidden,
                               out + OUT0 + (size_t)fidx * FEAT);
            ++fidx;
        }
    }
    hipLaunchKernelGGL(resid_ln_kernel, dim3(ROWS / 4), dim3(256), 0, stream, residual, hidden,
                       normf_w, normf_b, (unsigned short*)nullptr, out, ROWS);
}

// Round 18
// 5787.863 us; speedup vs baseline: 1.3689x; 1.3689x over previous
//
#include <hip/hip_runtime.h>
#include <math.h>

#define B_   32
#define L_   197
#define E_   384
#define DI_  768
#define DS_  16
#define DR_  24
#define NP_  196
#define ROWS (B_ * L_)         // 6304
#define OUT0 (ROWS * E_)       // 2420736
#define FEAT (B_ * E_ * NP_)   // 2408448
#define LOG2E 1.4426950408889634f

typedef __attribute__((ext_vector_type(8))) short bf16x8;
typedef __attribute__((ext_vector_type(4))) float f32x4;
typedef __attribute__((ext_vector_type(2))) __fp16 half2v;

#if __has_builtin(__builtin_amdgcn_exp2f)
#define EXP2(x) __builtin_amdgcn_exp2f(x)
#else
#define EXP2(x) __expf((x) * 0.6931471805599453f)
#endif

// async global->LDS, 16B per lane
__device__ __forceinline__ void gll16(const void* g, void* l) {
    __builtin_amdgcn_global_load_lds((const __attribute__((address_space(1))) void*)g,
                                     (__attribute__((address_space(3))) void*)l, 16, 0, 0);
}

__device__ __forceinline__ float silu_f(float x) { return x / (1.f + __expf(-x)); }

__device__ __forceinline__ unsigned short f2bf(float x) {
    unsigned int u = __float_as_uint(x);
    u += 0x7fffu + ((u >> 16) & 1u);
    return (unsigned short)(u >> 16);
}
__device__ __forceinline__ float bf2f(unsigned short u) {
    return __uint_as_float((unsigned int)u << 16);
}
__device__ __forceinline__ float bflo(unsigned int u) { return __uint_as_float(u << 16); }
__device__ __forceinline__ float bfhi(unsigned int u) {
    return __uint_as_float(u & 0xffff0000u);
}

// ---------------- fp32 -> bf16 bulk convert (weights; n % 4 == 0) ----------------
__global__ __launch_bounds__(256) void cvt_bf16_kernel(const float* __restrict__ in,
                                                       unsigned short* __restrict__ out,
                                                       int n4) {
    int idx = blockIdx.x * 256 + threadIdx.x;
    if (idx >= n4) return;
    float4 v = *(const float4*)&in[idx * 4];
    ushort4 o = {f2bf(v.x), f2bf(v.y), f2bf(v.z), f2bf(v.w)};
    *(ushort4*)&out[idx * 4] = o;
}

// ---------------- im2col for patch embedding ----------------
__global__ __launch_bounds__(256) void im2col_kernel(const float* __restrict__ x,
                                                     float* __restrict__ xcol) {
    int idx = blockIdx.x * 256 + threadIdx.x;
    if (idx >= B_ * NP_ * 768) return;
    int k = idx % 768;
    int bp = idx / 768;
    int pi = bp % NP_, b = bp / NP_;
    int gi = pi / 14, gj = pi % 14;
    int c = k >> 8, r = k & 255, p = r >> 4, q = r & 15;
    xcol[idx] = x[((size_t)(b * 3 + c) * 224 + gi * 16 + p) * 224 + gj * 16 + q];
}

// ---------------- assemble hidden: patches + cls + pos ----------------
__global__ __launch_bounds__(256) void assemble_kernel(const float* __restrict__ patchbuf,
                                                       const float* __restrict__ cls,
                                                       const float* __restrict__ pos,
                                                       float* __restrict__ hidden) {
    int idx = blockIdx.x * 256 + threadIdx.x;
    if (idx >= ROWS * E_) return;
    int e = idx % E_;
    int bt = idx / E_;
    int tok = bt % L_, b = bt / L_;
    float v;
    if (tok == 98) v = cls[e];
    else {
        int pi = tok < 98 ? tok : tok - 1;
        v = patchbuf[(size_t)(b * NP_ + pi) * E_ + e];
    }
    hidden[idx] = v + pos[tok * E_ + e];
}

// ---------------- 128x128 bf16 MFMA GEMM, global_load_lds staging ----------------
__global__ __launch_bounds__(256) void gemm128_kernel(
    const void* Av, int lda, const unsigned short* __restrict__ W,
    const float* __restrict__ bias, void* C, unsigned short* __restrict__ aux,
    int ldc, int M, int N, int K, int amode, int cmode) {
    __shared__ unsigned short As[128][32];
    __shared__ unsigned short Ws[128][32];
    const int tid = threadIdx.x;
    const int wave = tid >> 6, lane = tid & 63;
    const int wr = wave >> 1, wc = wave & 1;
    const int bm = blockIdx.y * 128, bn = blockIdx.x * 128;
    const int fr = lane & 15, fq = lane >> 4;
    f32x4 acc[4][4] = {};

    for (int k0 = 0; k0 < K; k0 += 32) {
        __syncthreads();
        if (amode == 4) {
            const unsigned short* A = (const unsigned short*)Av;
#pragma unroll
            for (int it = 0; it < 2; ++it) {
                int c = it * 256 + tid;
                int row = c >> 2, kq = c & 3;
                gll16(&A[(size_t)(bm + row) * lda + k0 + kq * 8], &As[row][kq * 8]);
            }
        } else {
            const float* A = (const float*)Av;
            const int r = tid >> 3, c4 = tid & 7;
            const int kbase = k0 + c4 * 4;
#pragma unroll
            for (int it = 0; it < 4; ++it) {
                int row = it * 32 + r;
                int gm = bm + row;
                ushort4 ua = {0, 0, 0, 0};
                if (gm < M) {
                    float4 va = *(const float4*)&A[(size_t)gm * lda + kbase];
                    ua.x = f2bf(va.x); ua.y = f2bf(va.y);
                    ua.z = f2bf(va.z); ua.w = f2bf(va.w);
                }
                *(ushort4*)&As[row][c4 * 4] = ua;
            }
        }
#pragma unroll
        for (int it = 0; it < 2; ++it) {
            int c = it * 256 + tid;
            int row = c >> 2, kq = c & 3;
            gll16(&W[(size_t)(bn + row) * K + k0 + kq * 8], &Ws[row][kq * 8]);
        }
        __syncthreads();
        bf16x8 af[4], bfr[4];
#pragma unroll
        for (int i = 0; i < 4; ++i) {
            af[i]  = *(const bf16x8*)&As[wr * 64 + i * 16 + fr][fq * 8];
            bfr[i] = *(const bf16x8*)&Ws[wc * 64 + i * 16 + fr][fq * 8];
        }
#pragma unroll
        for (int i = 0; i < 4; ++i)
#pragma unroll
            for (int j = 0; j < 4; ++j)
                acc[i][j] =
                    __builtin_amdgcn_mfma_f32_16x16x32_bf16(af[i], bfr[j], acc[i][j], 0, 0, 0);
    }

#pragma unroll
    for (int j = 0; j < 4; ++j) {
        int n = bn + wc * 64 + j * 16 + fr;
        if (n >= N) continue;
        float bv = bias ? bias[n] : 0.f;
#pragma unroll
        for (int i = 0; i < 4; ++i) {
#pragma unroll
            for (int rr = 0; rr < 4; ++rr) {
                int m = bm + wr * 64 + i * 16 + fq * 4 + rr;
                if (m < M) {
                    float v = acc[i][j][rr] + bv;
                    if (cmode == 0) ((float*)C)[(size_t)m * ldc + n] = v;
                    else {
                        ((unsigned short*)C)[(size_t)m * ldc + n] = f2bf(v);
                        if (cmode == 2 && n >= 768)
                            aux[(size_t)m * 768 + (n - 768)] = f2bf(silu_f(v));
                    }
                }
            }
        }
    }
}

// ---------------- 64x64 bf16 MFMA GEMM (skinny shapes), gll staging ----------------
__global__ __launch_bounds__(256) void gemm64_kernel(
    const void* A0v, const void* A1v, int lda,
    const unsigned short* __restrict__ W0, const unsigned short* __restrict__ W1,
    void* C0, void* C1, int ldc, int M, int N, int K, int amode, int cmode) {
    __shared__ unsigned short As[64][32];
    __shared__ unsigned short Ws[64][32];
    const int tid = threadIdx.x;
    const int wave = tid >> 6, lane = tid & 63;
    const int wr = wave >> 1, wc = wave & 1;
    const int bm = blockIdx.y * 64, bn = blockIdx.x * 64;
    const int fr = lane & 15, fq = lane >> 4;
    const int row = tid >> 2, kq = tid & 3;
    const unsigned short* W = blockIdx.z ? W1 : W0;
    void* C = blockIdx.z ? C1 : C0;
    const void* Av = blockIdx.z ? A1v : A0v;
    f32x4 acc[2][2] = {};

    for (int k0 = 0; k0 < K; k0 += 32) {
        __syncthreads();
        if (amode == 4) {
            const unsigned short* A = (const unsigned short*)Av;
            gll16(&A[(size_t)(bm + row) * lda + k0 + kq * 8], &As[row][kq * 8]);
        } else {
            const unsigned short* Af = (const unsigned short*)A0v;
            const unsigned short* Ab = (const unsigned short*)A1v;
            int gm = bm + row;
            ushort4 a0 = {0, 0, 0, 0}, a1 = {0, 0, 0, 0};
            if (gm < M) {
                size_t off = (size_t)gm * lda + k0 + kq * 8;
                ushort4 f0 = *(const ushort4*)&Af[off];
                ushort4 b0 = *(const ushort4*)&Ab[off];
                ushort4 f1 = *(const ushort4*)&Af[off + 4];
                ushort4 b1 = *(const ushort4*)&Ab[off + 4];
                a0.x = f2bf((bf2f(f0.x) + bf2f(b0.x)) * 0.5f);
                a0.y = f2bf((bf2f(f0.y) + bf2f(b0.y)) * 0.5f);
                a0.z = f2bf((bf2f(f0.z) + bf2f(b0.z)) * 0.5f);
                a0.w = f2bf((bf2f(f0.w) + bf2f(b0.w)) * 0.5f);
                a1.x = f2bf((bf2f(f1.x) + bf2f(b1.x)) * 0.5f);
                a1.y = f2bf((bf2f(f1.y) + bf2f(b1.y)) * 0.5f);
                a1.z = f2bf((bf2f(f1.z) + bf2f(b1.z)) * 0.5f);
                a1.w = f2bf((bf2f(f1.w) + bf2f(b1.w)) * 0.5f);
            }
            *(ushort4*)&As[row][kq * 8] = a0;
            *(ushort4*)&As[row][kq * 8 + 4] = a1;
        }
        gll16(&W[(size_t)(bn + row) * K + k0 + kq * 8], &Ws[row][kq * 8]);
        __syncthreads();
        bf16x8 af[2], bfr[2];
#pragma unroll
        for (int i = 0; i < 2; ++i) {
            af[i]  = *(const bf16x8*)&As[wr * 32 + i * 16 + fr][fq * 8];
            bfr[i] = *(const bf16x8*)&Ws[wc * 32 + i * 16 + fr][fq * 8];
        }
#pragma unroll
        for (int i = 0; i < 2; ++i)
#pragma unroll
            for (int j = 0; j < 2; ++j)
                acc[i][j] =
                    __builtin_amdgcn_mfma_f32_16x16x32_bf16(af[i], bfr[j], acc[i][j], 0, 0, 0);
    }

#pragma unroll
    for (int j = 0; j < 2; ++j) {
        int n = bn + wc * 32 + j * 16 + fr;
        if (n >= N) continue;
#pragma unroll
        for (int i = 0; i < 2; ++i) {
#pragma unroll
            for (int rr = 0; rr < 4; ++rr) {
                int m = bm + wr * 32 + i * 16 + fq * 4 + rr;
                if (m < M) {
                    float v = acc[i][j][rr];
                    if (cmode == 0) ((float*)C)[(size_t)m * ldc + n] = v;
                    else ((unsigned short*)C)[(size_t)m * ldc + n] = f2bf(v);
                }
            }
        }
    }
}

// ------- fused residual += hidden ; hn(bf16) = LayerNorm(residual) -------------------
__global__ __launch_bounds__(256) void resid_ln_kernel(float* __restrict__ residual,
                                                       const float* __restrict__ hidden,
                                                       const float* __restrict__ w,
                                                       const float* __restrict__ b,
                                                       unsigned short* __restrict__ outb,
                                                       float* __restrict__ outf,
                                                       int nrows) {
    int row = blockIdx.x * 4 + (threadIdx.x >> 6);
    int lane = threadIdx.x & 63;
    if (row >= nrows) return;
    const float* rp = residual + (size_t)row * E_;
    const float* hp = hidden + (size_t)row * E_;
    float v[6];
    float sum = 0.f;
#pragma unroll
    for (int i = 0; i < 6; ++i) {
        int c = lane + i * 64;
        float x = rp[c] + hp[c];
        v[i] = x;
        sum += x;
    }
#pragma unroll
    for (int o = 32; o; o >>= 1) sum += __shfl_xor(sum, o);
    float mean = sum * (1.f / E_);
    float vs = 0.f;
#pragma unroll
    for (int i = 0; i < 6; ++i) {
        float d = v[i] - mean;
        vs += d * d;
    }
#pragma unroll
    for (int o = 32; o; o >>= 1) vs += __shfl_xor(vs, o);
    float rstd = rsqrtf(vs * (1.f / E_) + 1e-5f);
#pragma unroll
    for (int i = 0; i < 6; ++i) {
        int c = lane + i * 64;
        residual[(size_t)row * E_ + c] = v[i];
        float o = (v[i] - mean) * rstd * w[c] + b[c];
        if (outb) outb[(size_t)row * E_ + c] = f2bf(o);
        else outf[(size_t)row * E_ + c] = o;
    }
}

// ------- causal conv1d + SiLU -> bf16, 4 d's/thread (z handled by in_proj epilogue) ---
__global__ __launch_bounds__(256) void conv_silu4_kernel(const unsigned short* __restrict__ xz,
                                                         const float* __restrict__ cw_f,
                                                         const float* __restrict__ cb_f,
                                                         const float* __restrict__ cw_b,
                                                         const float* __restrict__ cb_b,
                                                         unsigned short* __restrict__ xc_f,
                                                         unsigned short* __restrict__ xc_b) {
    int rev = blockIdx.y;
    const float* cw = rev ? cw_b : cw_f;
    const float* cb = rev ? cb_b : cb_f;
    unsigned short* xc = rev ? xc_b : xc_f;
    int idx = blockIdx.x * 256 + threadIdx.x;      // over B_*L_*DI_/4
    if (idx >= B_ * L_ * DI_ / 4) return;
    int d4 = idx % (DI_ / 4);
    int bt = idx / (DI_ / 4);
    int t = bt % L_, b = bt / L_;
    int d = d4 * 4;
    float4 w0 = *(const float4*)&cw[(d + 0) * 4];
    float4 w1 = *(const float4*)&cw[(d + 1) * 4];
    float4 w2 = *(const float4*)&cw[(d + 2) * 4];
    float4 w3 = *(const float4*)&cw[(d + 3) * 4];
    float4 cbv = *(const float4*)&cb[d];
    float acc0 = cbv.x, acc1 = cbv.y, acc2 = cbv.z, acc3 = cbv.w;
#pragma unroll
    for (int k = 0; k < 4; ++k) {
        int tt = t - 3 + k;
        if (tt >= 0) {
            int pos = rev ? (L_ - 1 - tt) : tt;
            ushort4 xv = *(const ushort4*)&xz[(size_t)(b * L_ + pos) * 1536 + d];
            float wk0 = (&w0.x)[k], wk1 = (&w1.x)[k], wk2 = (&w2.x)[k], wk3 = (&w3.x)[k];
            acc0 += wk0 * bf2f(xv.x);
            acc1 += wk1 * bf2f(xv.y);
            acc2 += wk2 * bf2f(xv.z);
            acc3 += wk3 * bf2f(xv.w);
        }
    }
    ushort4 o = {f2bf(silu_f(acc0)), f2bf(silu_f(acc1)), f2bf(silu_f(acc2)),
                 f2bf(silu_f(acc3))};
    *(ushort4*)&xc[(size_t)bt * DI_ + d] = o;
}

// ---------------- chunk-parallel SSM scan, 8 d's/block, XCD-affinity swizzle ----------
// f16 a-cache in VGPRs: pass 1 computes+packs decay factors; pass 2 replays without exp.
// B/C interleaved in LDS as {Bpair,Cpair} 8B records -> 1 ds_read_b64 per 2 t in pass 2.
__global__ __launch_bounds__(512, 8) void scan8_kernel(
    const unsigned short* __restrict__ xcl_f, const unsigned short* __restrict__ xcl_b,
    const unsigned short* __restrict__ xdbl_f, const unsigned short* __restrict__ xdbl_b,
    const unsigned short* __restrict__ zsilu,
    const float* __restrict__ dtw_f, const float* __restrict__ dtw_b,
    const float* __restrict__ dtb_f, const float* __restrict__ dtb_b,
    const float* __restrict__ Alog_f, const float* __restrict__ Alog_b,
    const float* __restrict__ Dv_f, const float* __restrict__ Dv_b,
    unsigned short* __restrict__ yout_f, unsigned short* __restrict__ yout_b) {
    int bid = blockIdx.x;
    int xcd = bid & 7;
    int rdec = bid >> 3;
    int dg = rdec % 96;
    int ph = rdec / 96;
    int p = ph * 8 + xcd;
    const int b = p >> 1, dir = p & 1;
    const int d0 = dg * 8;

    const unsigned short* xcl = dir ? xcl_b : xcl_f;
    const unsigned short* xdbl = dir ? xdbl_b : xdbl_f;
    const float* dtw  = dir ? dtw_b : dtw_f;
    const float* dtbp = dir ? dtb_b : dtb_f;
    const float* Alog = dir ? Alog_b : Alog_f;
    const float* Dv   = dir ? Dv_b : Dv_f;
    unsigned short* yout = dir ? yout_b : yout_f;
    const int tid = threadIdx.x;

    __shared__ float dt_s[8][200];
    __shared__ unsigned short g_s[8][200];
    __shared__ unsigned short u_s[8][200];
    __shared__ unsigned short z_s[8][200];
    __shared__ unsigned short y_s[8][200];
    // BCs[n]: 106 records of {B[2q],B[2q+1],C[2q],C[2q+1]} (4 shorts = 8 B)
    __shared__ unsigned short BCs[16][424];
    __shared__ float Ps[8][4][16], Ss[8][4][16], hin[8][4][16];
    __shared__ float dtw_s[8][24];

    if (tid < 192) dtw_s[tid / 24][tid % 24] = dtw[(d0 + tid / 24) * 24 + tid % 24];
    __syncthreads();

    // stage B, C (pure bf16 copy into interleaved records)
    for (int e = tid; e < 3200; e += 512) {
        int t = e >> 4, nn = e & 15;
        unsigned short Bv = 0, Cv = 0;
        if (t < L_) {
            const unsigned short* xr = &xdbl[(size_t)(b * L_ + t) * 56];
            Bv = xr[24 + nn];
            Cv = xr[40 + nn];
        }
        int base = (t >> 1) * 4 + (t & 1);
        BCs[nn][base] = Bv;
        BCs[nn][base + 2] = Cv;
    }
    // stage dt (f32 from bf16 inputs), g=dt*u, u, z
    for (int e = tid; e < 800; e += 512) {
        int dd = e & 7, q = e >> 3;
        float dtv[2], uv[2], zv[2];
#pragma unroll
        for (int h = 0; h < 2; ++h) {
            int t = 2 * q + h;
            dtv[h] = 0.f; uv[h] = 0.f; zv[h] = 0.f;
            if (t < L_) {
                size_t row = (size_t)(b * L_ + t);
                int pos = dir ? (L_ - 1 - t) : t;
                uv[h] = bf2f(xcl[row * DI_ + d0 + dd]);
                zv[h] = bf2f(zsilu[(size_t)(b * L_ + pos) * DI_ + d0 + dd]);
                const unsigned short* xr = &xdbl[row * 56];
                float acc = dtbp[d0 + dd];
#pragma unroll
                for (int rr = 0; rr < 24; ++rr) acc += bf2f(xr[rr]) * dtw_s[dd][rr];
                dtv[h] = (acc > 20.f) ? acc : log1pf(__expf(acc));
            }
        }
        *(float2*)&dt_s[dd][2 * q] = make_float2(dtv[0], dtv[1]);
        ushort2 ug = {f2bf(dtv[0] * uv[0]), f2bf(dtv[1] * uv[1])};
        ushort2 uu = {f2bf(uv[0]), f2bf(uv[1])};
        ushort2 uz = {f2bf(zv[0]), f2bf(zv[1])};
        *(ushort2*)&g_s[dd][2 * q] = ug;
        *(ushort2*)&u_s[dd][2 * q] = uu;
        *(ushort2*)&z_s[dd][2 * q] = uz;
    }
    __syncthreads();

    const int dd = tid >> 6;
    const int tt = (tid >> 4) & 3;
    const int n = tid & 15;
    const float An = -__expf(Alog[(d0 + dd) * DS_ + n]) * LOG2E;
    const int t0 = tt * 50;            // even -> pair-aligned

    const float* dtp = &dt_s[dd][t0];
    const unsigned short* gp = &g_s[dd][t0];
    const unsigned short* BCp = &BCs[n][(t0 >> 1) * 4];

    // pass 1: chunk (P,S) in f32; cache a-pairs as f16 in VGPRs
    half2v acache[25];
    float P = 1.f, S = 0.f;
#pragma unroll
    for (int i = 0; i < 50; i += 2) {
        float2 dt2 = *(const float2*)&dtp[i];
        unsigned int g2 = *(const unsigned int*)&gp[i];
        unsigned int B2 = *(const unsigned int*)&BCp[(i >> 1) * 4];
        float a0 = EXP2(dt2.x * An);
        float a1 = EXP2(dt2.y * An);
        acache[i >> 1] = __builtin_amdgcn_cvt_pkrtz(a0, a1);
        S = S * a0 + bflo(g2) * bflo(B2);
        S = S * a1 + bfhi(g2) * bfhi(B2);
        P *= a0 * a1;
    }
    Ps[dd][tt][n] = P;
    Ss[dd][tt][n] = S;
    __syncthreads();
    if (tid < 128) {
        int cdd = tid >> 4, cn = tid & 15;
        float h = 0.f;
#pragma unroll
        for (int c = 0; c < 4; ++c) {
            hin[cdd][c][cn] = h;
            h = Ps[cdd][c][cn] * h + Ss[cdd][c][cn];
        }
    }
    __syncthreads();

    // pass 2: replay with cached f16 a; 3 groups of 16 t + 2-t tail
    float h = hin[dd][tt][n];
    const float Dval = Dv[d0 + dd];
    const bool up8 = (n & 8) != 0;
    const bool up4 = (n & 4) != 0;
    const bool up2 = (n & 2) != 0;
    const bool up1 = (n & 1) != 0;
#pragma unroll
    for (int grp = 0; grp < 3; ++grp) {
        const int base = grp * 16;
        float pv[16];
#pragma unroll
        for (int i = 0; i < 16; i += 2) {
            const int q = (base + i) >> 1;
            unsigned int g2 = *(const unsigned int*)&gp[base + i];
            uint2 bc = *(const uint2*)&BCp[q * 4];
            half2v ah = acache[q];
            h = (float)ah.x * h + bflo(g2) * bflo(bc.x);
            pv[i] = h * bflo(bc.y);
            h = (float)ah.y * h + bfhi(g2) * bfhi(bc.x);
            pv[i + 1] = h * bfhi(bc.y);
        }
#pragma unroll
        for (int j = 0; j < 8; ++j) {
            float send = up8 ? pv[j] : pv[j + 8];
            float recv = __shfl_xor(send, 8);
            pv[j] = (up8 ? pv[j + 8] : pv[j]) + recv;
        }
#pragma unroll
        for (int j = 0; j < 4; ++j) {
            float send = up4 ? pv[j] : pv[j + 4];
            float recv = __shfl_xor(send, 4);
            pv[j] = (up4 ? pv[j + 4] : pv[j]) + recv;
        }
#pragma unroll
        for (int j = 0; j < 2; ++j) {
            float send = up2 ? pv[j] : pv[j + 2];
            float recv = __shfl_xor(send, 2);
            pv[j] = (up2 ? pv[j + 2] : pv[j]) + recv;
        }
        {
            float send = up1 ? pv[0] : pv[1];
            float recv = __shfl_xor(send, 1);
            pv[0] = (up1 ? pv[1] : pv[0]) + recv;
        }
        int t = t0 + base + n;
        if (t < L_) {
            float yv = (pv[0] + bf2f(u_s[dd][t]) * Dval) * bf2f(z_s[dd][t]);
            y_s[dd][t] = f2bf(yv);
        }
    }
    // tail: t = t0+48, t0+49
    {
        unsigned int g2 = *(const unsigned int*)&gp[48];
        uint2 bc = *(const uint2*)&BCp[24 * 4];
        half2v ah = acache[24];
#pragma unroll
        for (int half = 0; half < 2; ++half) {
            float av = half ? (float)ah.y : (float)ah.x;
            float gv = half ? bfhi(g2) : bflo(g2);
            float Bv = half ? bfhi(bc.x) : bflo(bc.x);
            float Cv = half ? bfhi(bc.y) : bflo(bc.y);
            h = av * h + gv * Bv;
            float y = h * Cv;
            y += __shfl_xor(y, 1);
            y += __shfl_xor(y, 2);
            y += __shfl_xor(y, 4);
            y += __shfl_xor(y, 8);
            int t = t0 + 48 + half;
            if (n == 0 && t < L_)
                y_s[dd][t] = f2bf((y + bf2f(u_s[dd][t]) * Dval) * bf2f(z_s[dd][t]));
        }
    }
    __syncthreads();
    for (int e = tid; e < 1600; e += 512) {
        int dd2 = e & 7, t = e >> 3;
        if (t < L_) {
            int pos = dir ? (L_ - 1 - t) : t;
            yout[(size_t)(b * L_ + pos) * DI_ + d0 + dd2] = y_s[dd2][t];
        }
    }
}

// ---------------- feature extraction ----------------
__global__ __launch_bounds__(256) void feat_kernel(const float* __restrict__ hidden,
                                                   float* __restrict__ out) {
    int idx = blockIdx.x * 256 + threadIdx.x;
    if (idx >= FEAT) return;
    int p = idx % NP_;
    int be = idx / NP_;
    int e = be % E_, b = be / E_;
    int tok = p < 98 ? p : p + 1;
    out[idx] = hidden[(size_t)(b * L_ + tok) * E_ + e];
}

extern "C" void kernel_launch(void* const* d_in, const int* in_sizes, int n_in, void* d_out,
                              int out_size, void* d_ws, size_t ws_size, hipStream_t stream) {
    const float* x        = (const float*)d_in[0];
    const float* patch_w  = (const float*)d_in[1];
    const float* patch_b  = (const float*)d_in[2];
    const float* cls_tok  = (const float*)d_in[3];
    const float* pos_emb  = (const float*)d_in[4];
    const float* norm_w   = (const float*)d_in[5];
    const float* norm_b   = (const float*)d_in[6];
    const float* in_proj  = (const float*)d_in[7];
    const float* conv_w   = (const float*)d_in[8];
    const float* conv_b   = (const float*)d_in[9];
    const float* xproj_w  = (const float*)d_in[10];
    const float* dtproj_w = (const float*)d_in[11];
    const float* dtproj_b = (const float*)d_in[12];
    const float* A_log    = (const float*)d_in[13];
    const float* D_param  = (const float*)d_in[14];
    const float* conv_wb  = (const float*)d_in[15];
    const float* conv_bb  = (const float*)d_in[16];
    const float* xproj_wb = (const float*)d_in[17];
    const float* dtproj_wb= (const float*)d_in[18];
    const float* dtproj_bb= (const float*)d_in[19];
    const float* A_logb   = (const float*)d_in[20];
    const float* D_paramb = (const float*)d_in[21];
    const float* out_proj = (const float*)d_in[22];
    const float* normf_w  = (const float*)d_in[23];
    const float* normf_b  = (const float*)d_in[24];
    float* out = (float*)d_out;

    float* ws       = (float*)d_ws;
    float* residual = ws;                                    // 9.68 MB
    float* hidden   = residual + OUT0;                       // 9.68 MB
    unsigned short* xz = (unsigned short*)(hidden + OUT0);   // 19.36 MB
    unsigned short* xcl_f = xz + (size_t)ROWS * 1536;        // 9.68 MB
    unsigned short* xcl_b = xcl_f + (size_t)ROWS * DI_;      // 9.68 MB
    unsigned short* zsilu = xcl_b + (size_t)ROWS * DI_;      // 9.68 MB
    unsigned short* xdbl_f = zsilu + (size_t)ROWS * DI_;     // 0.71 MB (bf16)
    unsigned short* xdbl_b = xdbl_f + (size_t)ROWS * 56;     // 0.71 MB
    unsigned short* yout_f = xdbl_b + (size_t)ROWS * 56;     // 9.68 MB
    unsigned short* yout_b = yout_f + (size_t)ROWS * DI_;    // 9.68 MB
    // pre-converted bf16 weights (~47.2 MB)
    unsigned short* wb_inproj  = yout_b + (size_t)ROWS * DI_;
    unsigned short* wb_outproj = wb_inproj + (size_t)24 * 1536 * E_;
    unsigned short* wb_xproj_f = wb_outproj + (size_t)24 * E_ * DI_;
    unsigned short* wb_xproj_b = wb_xproj_f + (size_t)24 * 56 * DI_;
    unsigned short* wb_patch   = wb_xproj_b + (size_t)24 * 56 * DI_;
    // overlays (timeline-disjoint)
    unsigned short* hn = yout_f;       // bf16; alive LN -> in_proj
    float* xcol     = (float*)xz;      // pre-layer only
    float* patchbuf = (float*)yout_f;  // pre-layer only

    hipMemsetAsync(residual, 0, (size_t)OUT0 * sizeof(float), stream);

    // weight conversion (once per launch)
    {
        int n;
        n = 24 * 1536 * E_ / 4;
        hipLaunchKernelGGL(cvt_bf16_kernel, dim3((n + 255) / 256), dim3(256), 0, stream,
                           in_proj, wb_inproj, n);
        n = 24 * E_ * DI_ / 4;
        hipLaunchKernelGGL(cvt_bf16_kernel, dim3((n + 255) / 256), dim3(256), 0, stream,
                           out_proj, wb_outproj, n);
        n = 24 * 56 * DI_ / 4;
        hipLaunchKernelGGL(cvt_bf16_kernel, dim3((n + 255) / 256), dim3(256), 0, stream,
                           xproj_w, wb_xproj_f, n);
        hipLaunchKernelGGL(cvt_bf16_kernel, dim3((n + 255) / 256), dim3(256), 0, stream,
                           xproj_wb, wb_xproj_b, n);
        n = E_ * 768 / 4;
        hipLaunchKernelGGL(cvt_bf16_kernel, dim3((n + 255) / 256), dim3(256), 0, stream,
                           patch_w, wb_patch, n);
    }

    // patch embedding
    hipLaunchKernelGGL(im2col_kernel, dim3((B_ * NP_ * 768 + 255) / 256), dim3(256), 0, stream,
                       x, xcol);
    {
        dim3 grid((E_ + 127) / 128, (B_ * NP_ + 127) / 128, 1);
        hipLaunchKernelGGL(gemm128_kernel, grid, dim3(256), 0, stream, (const void*)xcol, 768,
                           wb_patch, patch_b, (void*)patchbuf, (unsigned short*)nullptr, E_,
                           B_ * NP_, E_, 768, 0, 0);
    }
    hipLaunchKernelGGL(assemble_kernel, dim3((ROWS * E_ + 255) / 256), dim3(256), 0, stream,
                       patchbuf, cls_tok, pos_emb, hidden);

    int fidx = 0;
    for (int i = 0; i < 24; ++i) {
        hipLaunchKernelGGL(resid_ln_kernel, dim3(ROWS / 4), dim3(256), 0, stream, residual,
                           hidden, norm_w + i * E_, norm_b + i * E_, hn, (float*)nullptr,
                           ROWS);
        // in_proj: A = hn (bf16, gll), C = xz (bf16) + zsilu epilogue
        {
            dim3 grid((1536 + 127) / 128, (ROWS + 127) / 128, 1);
            hipLaunchKernelGGL(gemm128_kernel, grid, dim3(256), 0, stream, (const void*)hn, E_,
                               wb_inproj + (size_t)i * 1536 * E_, nullptr, (void*)xz, zsilu,
                               1536, ROWS, 1536, E_, 4, 2);
        }
        hipLaunchKernelGGL(conv_silu4_kernel, dim3(B_ * L_ * DI_ / 4 / 256, 2), dim3(256), 0,
                           stream, xz, conv_w + (size_t)i * DI_ * 4, conv_b + (size_t)i * DI_,
                           conv_wb + (size_t)i * DI_ * 4, conv_bb + (size_t)i * DI_, xcl_f,
                           xcl_b);
        // x_proj both dirs, 64x64 tiles (bf16 A gll, bf16 C)
        {
            dim3 grid(1, (ROWS + 63) / 64, 2);
            hipLaunchKernelGGL(gemm64_kernel, grid, dim3(256), 0, stream, (const void*)xcl_f,
                               (const void*)xcl_b, DI_, wb_xproj_f + (size_t)i * 56 * DI_,
                               wb_xproj_b + (size_t)i * 56 * DI_, (void*)xdbl_f,
                               (void*)xdbl_b, 56, ROWS, 56, DI_, 4, 1);
        }
        hipLaunchKernelGGL(scan8_kernel, dim3(6144), dim3(512), 0, stream, xcl_f, xcl_b,
                           xdbl_f, xdbl_b, zsilu, dtproj_w + (size_t)i * DI_ * DR_,
                           dtproj_wb + (size_t)i * DI_ * DR_, dtproj_b + (size_t)i * DI_,
                           dtproj_bb + (size_t)i * DI_, A_log + (size_t)i * DI_ * DS_,
                           A_logb + (size_t)i * DI_ * DS_, D_param + (size_t)i * DI_,
                           D_paramb + (size_t)i * DI_, yout_f, yout_b);
        // out_proj: A = 0.5*(yout_f + yout_b) (bf16), 64x64 tiles, C = hidden (f32)
        {
            dim3 grid((E_ + 63) / 64, (ROWS + 63) / 64, 1);
            hipLaunchKernelGGL(gemm64_kernel, grid, dim3(256), 0, stream, (const void*)yout_f,
                               (const void*)yout_b, DI_, wb_outproj + (size_t)i * E_ * DI_,
                               nullptr, (void*)hidden, nullptr, E_, ROWS, E_, DI_, 1, 0);
        }
        if (i == 5 || i == 11 || i == 17 || i == 23) {
            hipLaunchKernelGGL(feat_kernel, dim3(FEAT / 256), dim3(256), 0, stream, hidden,
                               out + OUT0 + (size_t)fidx * FEAT);
            ++fidx;
        }
    }
    hipLaunchKernelGGL(resid_ln_kernel, dim3(ROWS / 4), dim3(256), 0, stream, residual, hidden,
                       normf_w, normf_b, (unsigned short*)nullptr, out, ROWS);
}